// Round 3
// baseline (548.764 us; speedup 1.0000x reference)
//
#include <hip/hip_runtime.h>
#include <math.h>

#define NC 25
#define NHID 50
#define NB 32
#define NH 256
#define NW 256
#define NOH 252
#define NOW 252

#define CHUNK 28          // output rows per block
#define NCHUNK 9          // 9*28 = 252
#define INROWS 34         // CHUNK + 6 input rows (iy = r0-1 .. r0+32)

// ---------------------------------------------------------------------------
// Exact-accuracy GELU via Abramowitz-Stegun 7.1.26 erf (|err| <= 1.5e-7).
// Branchless: 1 v_rcp_f32 + 1 v_exp_f32 + ~12 FMAs, vs libm erff's ~40-50
// divergent instructions (both paths execute for N(0,~1) inputs).
// Validated in rounds 1-2: absmax unchanged (0.015625).
// ---------------------------------------------------------------------------
__device__ __forceinline__ float gelu_exact(float h)
{
    const float x  = h * 0.70710678118654752f;   // h / sqrt(2)
    const float ax = fabsf(x);
    const float t  = __builtin_amdgcn_rcpf(fmaf(0.3275911f, ax, 1.0f));
    float p = fmaf(1.061405429f, t, -1.453152027f);
    p = fmaf(p, t, 1.421413741f);
    p = fmaf(p, t, -0.284496736f);
    p = fmaf(p, t, 0.254829592f);
    p = p * t;
    const float e  = __builtin_amdgcn_exp2f(ax * ax * -1.4426950408889634f);
    float er = fmaf(-p, e, 1.0f);                // erf(|x|)
    er = copysignf(er, x);
    return 0.5f * h * (1.0f + er);
}

// ---------------------------------------------------------------------------
// conv pass: NR consecutive output rows starting at ring-local row `lbase+1`
// (lbase = first input row local index). Lane L covers output cols 4L..4L+3.
// Needs ring cols [4L+3 .. 4L+12] per input row. The two edge scalars are
// 8-way bank conflicts but only ~26% LDS-pipe utilization total — NOT the
// binder (round-2 lesson: "fixing" them via shuffle cost occupancy, net loss).
// ---------------------------------------------------------------------------
template<int NR>
__device__ __forceinline__ void conv_pass(
    const float (*ring)[264], const float* wgt, int lbase, int lane,
    float (*acc)[4])
{
#pragma unroll
    for (int r = 0; r < NR + 6; ++r) {
        const float* rp = &ring[lbase + r][4 * lane];
        float xv[13];
        xv[3] = rp[3];
        const float4 q1 = *(const float4*)(rp + 4);
        const float4 q2 = *(const float4*)(rp + 8);
        xv[4] = q1.x; xv[5] = q1.y; xv[6] = q1.z; xv[7] = q1.w;
        xv[8] = q2.x; xv[9] = q2.y; xv[10] = q2.z; xv[11] = q2.w;
        xv[12] = rp[12];
#pragma unroll
        for (int j = 0; j < NR; ++j) {
            const int ky = r - j;
            if (ky >= 0 && ky < 7) {
#pragma unroll
                for (int cc = 0; cc < 4; ++cc) {
                    float s = 0.f;
#pragma unroll
                    for (int kx = 0; kx < 7; ++kx)
                        s = fmaf(wgt[ky * 7 + kx], xv[cc + kx + 3], s);
                    acc[j][cc] += s;
                }
            }
        }
    }
}

// ---------------------------------------------------------------------------
// Kernel 1: one block per (plane, chunk). Computes partial 9-stats of
// g = gelu(conv7(x)+bias) over output rows [chunk*28, chunk*28+28).
// stats: T, R0, R251, C0, C251, g00, g0R, gR0, gRR  (zero where not in chunk)
// ---------------------------------------------------------------------------
__global__ __launch_bounds__(256) void stats_kernel(
    const float* __restrict__ x, const float* __restrict__ w7,
    const float* __restrict__ b7, float* __restrict__ partial)
{
    const int bid   = blockIdx.x;       // plane*NCHUNK + chunk
    const int plane = bid / NCHUNK;
    const int chunk = bid - plane * NCHUNK;
    const int c     = plane % NC;
    const int r0    = chunk * CHUNK;
    const float* xp = x + (size_t)plane * (NH * NW);

    float wgt[49];
#pragma unroll
    for (int i = 0; i < 49; ++i) wgt[i] = w7[c * 49 + i];   // wave-uniform -> SGPRs
    const float bias = b7[c];

    __shared__ __attribute__((aligned(16))) float ring[INROWS][264];
    __shared__ float red[4][9];

    const int tid  = threadIdx.x;
    const int wave = tid >> 6;
    const int lane = tid & 63;

    // ---- stage all INROWS input rows, float4 per thread, one barrier ----
    // ring col l <-> input col l-4. part p writes ring cols [4p,4p+4) i.e.
    // input cols [4p-4, 4p): p in [1,64] are interior aligned float4 loads.
    for (int idx = tid; idx < INROWS * 66; idx += 256) {
        const int row = idx / 66;
        const int p   = idx - row * 66;
        const int iy  = r0 - 1 + row;
        float4 v = make_float4(0.f, 0.f, 0.f, 0.f);
        if (p >= 1 && p <= 64 && iy >= 0 && iy < NH)
            v = *(const float4*)&xp[iy * NW + 4 * (p - 1)];
        *(float4*)&ring[row][4 * p] = v;
    }
    __syncthreads();

    // ---- compute: wave handles output rows r0 + wave*7 + [0,7) ----
    float tot = 0.f, r0s = 0.f, r251s = 0.f, c0s = 0.f, c251s = 0.f;
    float g00 = 0.f, g0R = 0.f, gR0 = 0.f, gRR = 0.f;

    if (lane < 63) {
        const int oyF0 = r0 + wave * 7;        // pass A: rows oyF0..+3
        const int oyF1 = oyF0 + 4;             // pass B: rows oyF1..+2

        // pass A (4 rows)
        {
            float acc[4][4];
#pragma unroll
            for (int j = 0; j < 4; ++j)
#pragma unroll
                for (int cc = 0; cc < 4; ++cc) acc[j][cc] = 0.f;
            conv_pass<4>(ring, wgt, oyF0 - r0, lane, acc);
#pragma unroll
            for (int j = 0; j < 4; ++j) {
                const int oy = oyF0 + j;
                float g[4];
#pragma unroll
                for (int cc = 0; cc < 4; ++cc)
                    g[cc] = gelu_exact(acc[j][cc] + bias);
                const float s4 = (g[0] + g[1]) + (g[2] + g[3]);
                tot += s4;
                if (lane == 0)  c0s   += g[0];
                if (lane == 62) c251s += g[3];
                if (oy == 0)   { r0s   += s4; if (lane == 0) g00 += g[0]; if (lane == 62) g0R += g[3]; }
                if (oy == 251) { r251s += s4; if (lane == 0) gR0 += g[0]; if (lane == 62) gRR += g[3]; }
            }
        }
        // pass B (3 rows)
        {
            float acc[3][4];
#pragma unroll
            for (int j = 0; j < 3; ++j)
#pragma unroll
                for (int cc = 0; cc < 4; ++cc) acc[j][cc] = 0.f;
            conv_pass<3>(ring, wgt, oyF1 - r0, lane, acc);
#pragma unroll
            for (int j = 0; j < 3; ++j) {
                const int oy = oyF1 + j;
                float g[4];
#pragma unroll
                for (int cc = 0; cc < 4; ++cc)
                    g[cc] = gelu_exact(acc[j][cc] + bias);
                const float s4 = (g[0] + g[1]) + (g[2] + g[3]);
                tot += s4;
                if (lane == 0)  c0s   += g[0];
                if (lane == 62) c251s += g[3];
                if (oy == 0)   { r0s   += s4; if (lane == 0) g00 += g[0]; if (lane == 62) g0R += g[3]; }
                if (oy == 251) { r251s += s4; if (lane == 0) gR0 += g[0]; if (lane == 62) gRR += g[3]; }
            }
        }
    }

    // ---- block reduction of the 9 stats ----
    float st[9] = {tot, r0s, r251s, c0s, c251s, g00, g0R, gR0, gRR};
#pragma unroll
    for (int i = 0; i < 9; ++i) {
        float v = st[i];
        for (int off = 32; off > 0; off >>= 1) v += __shfl_down(v, off, 64);
        st[i] = v;
    }
    if (lane == 0) {
#pragma unroll
        for (int i = 0; i < 9; ++i) red[wave][i] = st[i];
    }
    __syncthreads();
    if (tid < 9)
        partial[(size_t)bid * 9 + tid] =
            (red[0][tid] + red[1][tid]) + (red[2][tid] + red[3][tid]);
}

// ---------------------------------------------------------------------------
// Kernel 2: per-batch. Sum chunk partials (fixed order -> deterministic),
// reconstruct conv3 mean via inclusion-exclusion, MLP, sigmoid, rank.
// ---------------------------------------------------------------------------
__global__ __launch_bounds__(64) void mlp_kernel(
    const float* __restrict__ partial, const float* __restrict__ w3,
    const float* __restrict__ fc1w, const float* __restrict__ fc1b,
    const float* __restrict__ fc2w, const float* __restrict__ fc2b,
    float* __restrict__ idx_out, float* __restrict__ gate_ws,
    int* __restrict__ src_ws)
{
    const int b = blockIdx.x;
    const int t = threadIdx.x;
    __shared__ float mean_s[NC], hid_s[NHID], s_s[NC];

    if (t < NC) {
        const float* base = partial + (size_t)(b * NC + t) * NCHUNK * 9;
        double acc[9];
#pragma unroll
        for (int i = 0; i < 9; ++i) acc[i] = 0.0;
        for (int ch = 0; ch < NCHUNK; ++ch)
#pragma unroll
            for (int i = 0; i < 9; ++i) acc[i] += (double)base[ch * 9 + i];

        float T = (float)acc[0], R0 = (float)acc[1], R251 = (float)acc[2];
        float C0 = (float)acc[3], C251 = (float)acc[4];
        float g00 = (float)acc[5], g0R = (float)acc[6];
        float gR0 = (float)acc[7], gRR = (float)acc[8];

        float ER[3] = {R251, 0.f, R0};
        float EC[3] = {C251, 0.f, C0};
        float CR[3][3] = {{gRR, 0.f, gR0}, {0.f, 0.f, 0.f}, {g0R, 0.f, g00}};
        float m = 0.f;
#pragma unroll
        for (int ky = 0; ky < 3; ++ky)
#pragma unroll
            for (int kx = 0; kx < 3; ++kx) {
                float S = T - ER[ky] - EC[kx] + CR[ky][kx];
                m += w3[t * 9 + ky * 3 + kx] * S;
            }
        mean_s[t] = m * (1.0f / (252.0f * 252.0f));
    }
    __syncthreads();
    if (t < NHID) {
        float a = fc1b[t];
#pragma unroll
        for (int cc = 0; cc < NC; ++cc) a += mean_s[cc] * fc1w[t * NC + cc];
        hid_s[t] = fmaxf(a, 0.f);
    }
    __syncthreads();
    if (t < NC) {
        float a = fc2b[t];
#pragma unroll
        for (int j = 0; j < NHID; ++j) a += hid_s[j] * fc2w[t * NHID + j];
        s_s[t] = 1.0f / (1.0f + expf(-a));
    }
    __syncthreads();
    if (t < NC) {
        float s = s_s[t];
        int rank = 0;
        for (int c2 = 0; c2 < NC; ++c2) {
            float s2 = s_s[c2];
            if (s2 > s || (s2 == s && c2 < t)) rank++;
        }
        float gate = (s * s) / (s * s + 1e-8f);
        idx_out[b * NC + rank] = (float)t;
        gate_ws[b * NC + rank] = gate;
        src_ws[b * NC + rank]  = t;
    }
}

// ---------------------------------------------------------------------------
// Kernel 3: gather + scale. 4 segment-blocks per output slot.
// ---------------------------------------------------------------------------
__global__ __launch_bounds__(256) void gather_kernel(
    const float* __restrict__ x, const float* __restrict__ gate_ws,
    const int* __restrict__ src_ws, float* __restrict__ out)
{
    const int bid = blockIdx.x;
    const int seg = bid & 3;
    const int p   = bid >> 2;            // b*25 + j
    const int b   = p / NC;
    const int j   = p - b * NC;
    const int src = src_ws[p];
    const float gate = gate_ws[p];

    const float4* xp = (const float4*)(x + ((size_t)(b * NC + src)) * (NH * NW))
                       + seg * 4096;
    float* dst;
    if (j < 10) dst = out + ((size_t)(b * 10 + j)) * (NH * NW);
    else dst = out + (size_t)NB * 10 * (NH * NW) + ((size_t)(b * 15 + (j - 10))) * (NH * NW);
    float4* dp = (float4*)dst + seg * 4096;

    const int t = threadIdx.x;
#pragma unroll 4
    for (int i = t; i < 4096; i += 256) {
        float4 v = xp[i];
        v.x *= gate; v.y *= gate; v.z *= gate; v.w *= gate;
        dp[i] = v;
    }
}

extern "C" void kernel_launch(void* const* d_in, const int* in_sizes, int n_in,
                              void* d_out, int out_size, void* d_ws, size_t ws_size,
                              hipStream_t stream)
{
    const float* x    = (const float*)d_in[0];
    const float* w7   = (const float*)d_in[1];
    const float* b7   = (const float*)d_in[2];
    const float* w3   = (const float*)d_in[3];
    const float* fc1w = (const float*)d_in[4];
    const float* fc1b = (const float*)d_in[5];
    const float* fc2w = (const float*)d_in[6];
    const float* fc2b = (const float*)d_in[7];
    float* out = (float*)d_out;

    float* partial = (float*)d_ws;                        // 800*9*9 floats
    float* gate_ws = partial + NB * NC * NCHUNK * 9;      // 800 floats
    int*   src_ws  = (int*)(gate_ws + NB * NC);           // 800 ints

    float* idx_out = out + (size_t)NB * 10 * (NH * NW) + (size_t)NB * 15 * (NH * NW);

    stats_kernel<<<NB * NC * NCHUNK, 256, 0, stream>>>(x, w7, b7, partial);
    mlp_kernel<<<NB, 64, 0, stream>>>(partial, w3, fc1w, fc1b, fc2w, fc2b,
                                      idx_out, gate_ws, src_ws);
    gather_kernel<<<NB * NC * 4, 256, 0, stream>>>(x, gate_ws, src_ws, out);
}

// Round 4
// 529.579 us; speedup vs baseline: 1.0362x; 1.0362x over previous
//
#include <hip/hip_runtime.h>
#include <math.h>

#define NC 25
#define NHID 50
#define NB 32
#define NH 256
#define NW 256
#define NOH 252
#define NOW 252

#define CHUNK 28          // output rows per block
#define NCHUNK 9          // 9*28 = 252
#define INROWS 34         // CHUNK + 6 input rows (iy = r0-1 .. r0+32)

// ---------------------------------------------------------------------------
// Exact-accuracy GELU via Abramowitz-Stegun 7.1.26 erf (|err| <= 1.5e-7).
// Branchless: 1 v_rcp_f32 + 1 v_exp_f32 + ~12 FMAs. Validated rounds 1-3:
// absmax unchanged (0.015625).
// ---------------------------------------------------------------------------
__device__ __forceinline__ float gelu_exact(float h)
{
    const float x  = h * 0.70710678118654752f;   // h / sqrt(2)
    const float ax = fabsf(x);
    const float t  = __builtin_amdgcn_rcpf(fmaf(0.3275911f, ax, 1.0f));
    float p = fmaf(1.061405429f, t, -1.453152027f);
    p = fmaf(p, t, 1.421413741f);
    p = fmaf(p, t, -0.284496736f);
    p = fmaf(p, t, 0.254829592f);
    p = p * t;
    const float e  = __builtin_amdgcn_exp2f(ax * ax * -1.4426950408889634f);
    float er = fmaf(-p, e, 1.0f);                // erf(|x|)
    er = copysignf(er, x);
    return 0.5f * h * (1.0f + er);
}

// ---------------------------------------------------------------------------
// Kernel 1: one block per (plane, chunk). Partial 9-stats of
// g = gelu(conv7(x)+bias) over output rows [chunk*28, chunk*28+28).
//
// Round-4 structure: each wave owns 7 output rows, reads its 13 input rows
// ONCE in a single pass with a hand-written 1-deep LDS prefetch pipeline.
// sched_barrier(0) at each row boundary pins the schedule: 4 LDS reads per
// ~105 FMAs, load->use distance = one full row (covers ~120cy LDS latency),
// live window ~2 rows (stops the VGPR balloon seen in rounds 1-3).
// ---------------------------------------------------------------------------
__global__ __launch_bounds__(256) void stats_kernel(
    const float* __restrict__ x, const float* __restrict__ w7,
    const float* __restrict__ b7, float* __restrict__ partial)
{
    const int bid   = blockIdx.x;       // plane*NCHUNK + chunk
    const int plane = bid / NCHUNK;
    const int chunk = bid - plane * NCHUNK;
    const int c     = plane % NC;
    const int r0    = chunk * CHUNK;
    const float* xp = x + (size_t)plane * (NH * NW);

    float wgt[49];
#pragma unroll
    for (int i = 0; i < 49; ++i) wgt[i] = w7[c * 49 + i];   // wave-uniform -> SGPRs
    const float bias = b7[c];

    __shared__ __attribute__((aligned(16))) float ring[INROWS][264];
    __shared__ float red[4][9];

    const int tid  = threadIdx.x;
    const int wave = tid >> 6;
    const int lane = tid & 63;

    // ---- stage all INROWS input rows, float4 per thread, one barrier ----
    // ring col l <-> input col l-4. part p writes ring cols [4p,4p+4):
    // p in [1,64] interior aligned float4 loads; p=0 and p=65 write zero pads.
    for (int idx = tid; idx < INROWS * 66; idx += 256) {
        const int row = idx / 66;
        const int p   = idx - row * 66;
        const int iy  = r0 - 1 + row;
        float4 v = make_float4(0.f, 0.f, 0.f, 0.f);
        if (p >= 1 && p <= 64 && iy >= 0 && iy < NH)
            v = *(const float4*)&xp[iy * NW + 4 * (p - 1)];
        *(float4*)&ring[row][4 * p] = v;
    }
    __syncthreads();

    // ---- compute: wave handles output rows r0 + wave*7 + [0,7) ----
    float tot = 0.f, r0s = 0.f, r251s = 0.f, c0s = 0.f, c251s = 0.f;
    float g00 = 0.f, g0R = 0.f, gR0 = 0.f, gRR = 0.f;

    if (lane < 63) {
        const int lbase = wave * 7;            // ring row of first input row
        const int oy0   = r0 + wave * 7;       // first output row

        float acc[7][4];
#pragma unroll
        for (int j = 0; j < 7; ++j)
#pragma unroll
            for (int cc = 0; cc < 4; ++cc) acc[j][cc] = 0.f;

        // prefetch input row 0 of this wave's window
        float  e3, e12;
        float4 q1, q2;
        {
            const float* rp = &ring[lbase][4 * lane];
            e3  = rp[3];
            q1  = *(const float4*)(rp + 4);
            q2  = *(const float4*)(rp + 8);
            e12 = rp[12];
        }

#pragma unroll
        for (int r = 0; r < 13; ++r) {
            // take current row out of the prefetch regs
            float xv[13];
            xv[3] = e3;
            xv[4] = q1.x; xv[5] = q1.y; xv[6]  = q1.z; xv[7]  = q1.w;
            xv[8] = q2.x; xv[9] = q2.y; xv[10] = q2.z; xv[11] = q2.w;
            xv[12] = e12;
            // issue next row's loads (completion needed only next iteration)
            if (r < 12) {
                const float* rp = &ring[lbase + r + 1][4 * lane];
                e3  = rp[3];
                q1  = *(const float4*)(rp + 4);
                q2  = *(const float4*)(rp + 8);
                e12 = rp[12];
            }
            // FMAs for input row r: output row j gets kernel row ky = r - j
#pragma unroll
            for (int j = 0; j < 7; ++j) {
                const int ky = r - j;
                if (ky >= 0 && ky < 7) {
#pragma unroll
                    for (int cc = 0; cc < 4; ++cc) {
#pragma unroll
                        for (int kx = 0; kx < 7; ++kx)
                            acc[j][cc] = fmaf(wgt[ky * 7 + kx], xv[cc + kx + 3],
                                              acc[j][cc]);
                    }
                }
            }
            __builtin_amdgcn_sched_barrier(0);  // pin: nothing crosses rows
        }

        // ---- gelu + stats for the 7 output rows ----
#pragma unroll
        for (int j = 0; j < 7; ++j) {
            const int oy = oy0 + j;
            float g[4];
#pragma unroll
            for (int cc = 0; cc < 4; ++cc)
                g[cc] = gelu_exact(acc[j][cc] + bias);
            const float s4 = (g[0] + g[1]) + (g[2] + g[3]);
            tot += s4;
            if (lane == 0)  c0s   += g[0];
            if (lane == 62) c251s += g[3];
            if (oy == 0)   { r0s   += s4; if (lane == 0) g00 += g[0]; if (lane == 62) g0R += g[3]; }
            if (oy == 251) { r251s += s4; if (lane == 0) gR0 += g[0]; if (lane == 62) gRR += g[3]; }
        }
    }

    // ---- block reduction of the 9 stats ----
    float st[9] = {tot, r0s, r251s, c0s, c251s, g00, g0R, gR0, gRR};
#pragma unroll
    for (int i = 0; i < 9; ++i) {
        float v = st[i];
        for (int off = 32; off > 0; off >>= 1) v += __shfl_down(v, off, 64);
        st[i] = v;
    }
    if (lane == 0) {
#pragma unroll
        for (int i = 0; i < 9; ++i) red[wave][i] = st[i];
    }
    __syncthreads();
    if (tid < 9)
        partial[(size_t)bid * 9 + tid] =
            (red[0][tid] + red[1][tid]) + (red[2][tid] + red[3][tid]);
}

// ---------------------------------------------------------------------------
// Kernel 2: per-batch. Sum chunk partials (fixed order -> deterministic),
// reconstruct conv3 mean via inclusion-exclusion, MLP, sigmoid, rank.
// ---------------------------------------------------------------------------
__global__ __launch_bounds__(64) void mlp_kernel(
    const float* __restrict__ partial, const float* __restrict__ w3,
    const float* __restrict__ fc1w, const float* __restrict__ fc1b,
    const float* __restrict__ fc2w, const float* __restrict__ fc2b,
    float* __restrict__ idx_out, float* __restrict__ gate_ws,
    int* __restrict__ src_ws)
{
    const int b = blockIdx.x;
    const int t = threadIdx.x;
    __shared__ float mean_s[NC], hid_s[NHID], s_s[NC];

    if (t < NC) {
        const float* base = partial + (size_t)(b * NC + t) * NCHUNK * 9;
        double acc[9];
#pragma unroll
        for (int i = 0; i < 9; ++i) acc[i] = 0.0;
        for (int ch = 0; ch < NCHUNK; ++ch)
#pragma unroll
            for (int i = 0; i < 9; ++i) acc[i] += (double)base[ch * 9 + i];

        float T = (float)acc[0], R0 = (float)acc[1], R251 = (float)acc[2];
        float C0 = (float)acc[3], C251 = (float)acc[4];
        float g00 = (float)acc[5], g0R = (float)acc[6];
        float gR0 = (float)acc[7], gRR = (float)acc[8];

        float ER[3] = {R251, 0.f, R0};
        float EC[3] = {C251, 0.f, C0};
        float CR[3][3] = {{gRR, 0.f, gR0}, {0.f, 0.f, 0.f}, {g0R, 0.f, g00}};
        float m = 0.f;
#pragma unroll
        for (int ky = 0; ky < 3; ++ky)
#pragma unroll
            for (int kx = 0; kx < 3; ++kx) {
                float S = T - ER[ky] - EC[kx] + CR[ky][kx];
                m += w3[t * 9 + ky * 3 + kx] * S;
            }
        mean_s[t] = m * (1.0f / (252.0f * 252.0f));
    }
    __syncthreads();
    if (t < NHID) {
        float a = fc1b[t];
#pragma unroll
        for (int cc = 0; cc < NC; ++cc) a += mean_s[cc] * fc1w[t * NC + cc];
        hid_s[t] = fmaxf(a, 0.f);
    }
    __syncthreads();
    if (t < NC) {
        float a = fc2b[t];
#pragma unroll
        for (int j = 0; j < NHID; ++j) a += hid_s[j] * fc2w[t * NHID + j];
        s_s[t] = 1.0f / (1.0f + expf(-a));
    }
    __syncthreads();
    if (t < NC) {
        float s = s_s[t];
        int rank = 0;
        for (int c2 = 0; c2 < NC; ++c2) {
            float s2 = s_s[c2];
            if (s2 > s || (s2 == s && c2 < t)) rank++;
        }
        float gate = (s * s) / (s * s + 1e-8f);
        idx_out[b * NC + rank] = (float)t;
        gate_ws[b * NC + rank] = gate;
        src_ws[b * NC + rank]  = t;
    }
}

// ---------------------------------------------------------------------------
// Kernel 3: gather + scale. 4 segment-blocks per output slot.
// ---------------------------------------------------------------------------
__global__ __launch_bounds__(256) void gather_kernel(
    const float* __restrict__ x, const float* __restrict__ gate_ws,
    const int* __restrict__ src_ws, float* __restrict__ out)
{
    const int bid = blockIdx.x;
    const int seg = bid & 3;
    const int p   = bid >> 2;            // b*25 + j
    const int b   = p / NC;
    const int j   = p - b * NC;
    const int src = src_ws[p];
    const float gate = gate_ws[p];

    const float4* xp = (const float4*)(x + ((size_t)(b * NC + src)) * (NH * NW))
                       + seg * 4096;
    float* dst;
    if (j < 10) dst = out + ((size_t)(b * 10 + j)) * (NH * NW);
    else dst = out + (size_t)NB * 10 * (NH * NW) + ((size_t)(b * 15 + (j - 10))) * (NH * NW);
    float4* dp = (float4*)dst + seg * 4096;

    const int t = threadIdx.x;
#pragma unroll 4
    for (int i = t; i < 4096; i += 256) {
        float4 v = xp[i];
        v.x *= gate; v.y *= gate; v.z *= gate; v.w *= gate;
        dp[i] = v;
    }
}

extern "C" void kernel_launch(void* const* d_in, const int* in_sizes, int n_in,
                              void* d_out, int out_size, void* d_ws, size_t ws_size,
                              hipStream_t stream)
{
    const float* x    = (const float*)d_in[0];
    const float* w7   = (const float*)d_in[1];
    const float* b7   = (const float*)d_in[2];
    const float* w3   = (const float*)d_in[3];
    const float* fc1w = (const float*)d_in[4];
    const float* fc1b = (const float*)d_in[5];
    const float* fc2w = (const float*)d_in[6];
    const float* fc2b = (const float*)d_in[7];
    float* out = (float*)d_out;

    float* partial = (float*)d_ws;                        // 800*9*9 floats
    float* gate_ws = partial + NB * NC * NCHUNK * 9;      // 800 floats
    int*   src_ws  = (int*)(gate_ws + NB * NC);           // 800 ints

    float* idx_out = out + (size_t)NB * 10 * (NH * NW) + (size_t)NB * 15 * (NH * NW);

    stats_kernel<<<NB * NC * NCHUNK, 256, 0, stream>>>(x, w7, b7, partial);
    mlp_kernel<<<NB, 64, 0, stream>>>(partial, w3, fc1w, fc1b, fc2w, fc2b,
                                      idx_out, gate_ws, src_ws);
    gather_kernel<<<NB * NC * 4, 256, 0, stream>>>(x, gate_ws, src_ws, out);
}

// Round 5
// 470.707 us; speedup vs baseline: 1.1658x; 1.1251x over previous
//
#include <hip/hip_runtime.h>
#include <math.h>

#define NC 25
#define NHID 50
#define NB 32
#define NH 256
#define NW 256
#define NOH 252
#define NOW 252

#define CHUNK 12          // output rows per block
#define NCHUNK 21         // 21*12 = 252
#define INROWS 18         // CHUNK + 6 input rows (iy = r0-1 .. r0+16)

// ---------------------------------------------------------------------------
// Exact-accuracy GELU via Abramowitz-Stegun 7.1.26 erf (|err| <= 1.5e-7).
// Branchless: 1 v_rcp_f32 + 1 v_exp_f32 + ~12 FMAs. Validated rounds 1-4:
// absmax unchanged (0.015625). Cuts VALU-busy time ~26% vs libm erff.
// ---------------------------------------------------------------------------
__device__ __forceinline__ float gelu_exact(float h)
{
    const float x  = h * 0.70710678118654752f;   // h / sqrt(2)
    const float ax = fabsf(x);
    const float t  = __builtin_amdgcn_rcpf(fmaf(0.3275911f, ax, 1.0f));
    float p = fmaf(1.061405429f, t, -1.453152027f);
    p = fmaf(p, t, 1.421413741f);
    p = fmaf(p, t, -0.284496736f);
    p = fmaf(p, t, 0.254829592f);
    p = p * t;
    const float e  = __builtin_amdgcn_exp2f(ax * ax * -1.4426950408889634f);
    float er = fmaf(-p, e, 1.0f);                // erf(|x|)
    er = copysignf(er, x);
    return 0.5f * h * (1.0f + er);
}

// ---------------------------------------------------------------------------
// Kernel 1: one block per (plane, chunk). Partial 9-stats of
// g = gelu(conv7(x)+bias) over output rows [chunk*12, chunk*12+12).
//
// Round-5 structure: occupancy-first. LDS 19KB -> 8 blocks/CU; acc[3][4]
// (12 regs) + no prefetch regs + __launch_bounds__(256,8) -> VGPR<=64 ->
// 8 waves/SIMD. 32 waves/CU hide LDS/staging latency by TLP (m114: wave
// overlap captures what source pipelining would). sched_barrier(0) per row
// stops the scheduler's load-hoisting VGPR balloon (rounds 2-4 lesson).
// Accepted: rp[3]/rp[12] 8-way bank conflicts (LDS pipe ~25% util, not the
// binder — round-2 lesson).
// ---------------------------------------------------------------------------
__global__ __launch_bounds__(256, 8) void stats_kernel(
    const float* __restrict__ x, const float* __restrict__ w7,
    const float* __restrict__ b7, float* __restrict__ partial)
{
    const int bid   = blockIdx.x;       // plane*NCHUNK + chunk
    const int plane = bid / NCHUNK;
    const int chunk = bid - plane * NCHUNK;
    const int c     = plane % NC;
    const int r0    = chunk * CHUNK;
    const float* xp = x + (size_t)plane * (NH * NW);

    float wgt[49];
#pragma unroll
    for (int i = 0; i < 49; ++i) wgt[i] = w7[c * 49 + i];   // wave-uniform -> SGPRs
    const float bias = b7[c];

    __shared__ __attribute__((aligned(16))) float ring[INROWS][264];
    __shared__ float red[4][9];

    const int tid  = threadIdx.x;
    const int wave = tid >> 6;
    const int lane = tid & 63;

    // ---- stage all INROWS input rows, float4 per thread, one barrier ----
    // ring col l <-> input col l-4. part p writes ring cols [4p,4p+4):
    // p in [1,64] interior aligned float4 loads; p=0 and p=65 write zero pads.
    for (int idx = tid; idx < INROWS * 66; idx += 256) {
        const int row = idx / 66;
        const int p   = idx - row * 66;
        const int iy  = r0 - 1 + row;
        float4 v = make_float4(0.f, 0.f, 0.f, 0.f);
        if (p >= 1 && p <= 64 && iy >= 0 && iy < NH)
            v = *(const float4*)&xp[iy * NW + 4 * (p - 1)];
        *(float4*)&ring[row][4 * p] = v;
    }
    __syncthreads();

    // ---- compute: wave handles output rows r0 + wave*3 + [0,3) ----
    float tot = 0.f, r0s = 0.f, r251s = 0.f, c0s = 0.f, c251s = 0.f;
    float g00 = 0.f, g0R = 0.f, gR0 = 0.f, gRR = 0.f;

    if (lane < 63) {
        const int lbase = wave * 3;            // ring row of first input row
        const int oy0   = r0 + wave * 3;       // first output row

        float acc[3][4];
#pragma unroll
        for (int j = 0; j < 3; ++j)
#pragma unroll
            for (int cc = 0; cc < 4; ++cc) acc[j][cc] = 0.f;

#pragma unroll
        for (int r = 0; r < 9; ++r) {
            const float* rp = &ring[lbase + r][4 * lane];
            float xv[13];
            xv[3] = rp[3];
            const float4 q1 = *(const float4*)(rp + 4);
            const float4 q2 = *(const float4*)(rp + 8);
            xv[4] = q1.x; xv[5] = q1.y; xv[6]  = q1.z; xv[7]  = q1.w;
            xv[8] = q2.x; xv[9] = q2.y; xv[10] = q2.z; xv[11] = q2.w;
            xv[12] = rp[12];
            // FMAs for input row r: output row j gets kernel row ky = r - j
#pragma unroll
            for (int j = 0; j < 3; ++j) {
                const int ky = r - j;
                if (ky >= 0 && ky < 7) {
#pragma unroll
                    for (int cc = 0; cc < 4; ++cc) {
#pragma unroll
                        for (int kx = 0; kx < 7; ++kx)
                            acc[j][cc] = fmaf(wgt[ky * 7 + kx], xv[cc + kx + 3],
                                              acc[j][cc]);
                    }
                }
            }
            __builtin_amdgcn_sched_barrier(0);  // pin: nothing crosses rows
        }

        // ---- gelu + stats for the 3 output rows ----
#pragma unroll
        for (int j = 0; j < 3; ++j) {
            const int oy = oy0 + j;
            float g[4];
#pragma unroll
            for (int cc = 0; cc < 4; ++cc)
                g[cc] = gelu_exact(acc[j][cc] + bias);
            const float s4 = (g[0] + g[1]) + (g[2] + g[3]);
            tot += s4;
            if (lane == 0)  c0s   += g[0];
            if (lane == 62) c251s += g[3];
            if (oy == 0)   { r0s   += s4; if (lane == 0) g00 += g[0]; if (lane == 62) g0R += g[3]; }
            if (oy == 251) { r251s += s4; if (lane == 0) gR0 += g[0]; if (lane == 62) gRR += g[3]; }
        }
    }

    // ---- block reduction of the 9 stats ----
    float st[9] = {tot, r0s, r251s, c0s, c251s, g00, g0R, gR0, gRR};
#pragma unroll
    for (int i = 0; i < 9; ++i) {
        float v = st[i];
        for (int off = 32; off > 0; off >>= 1) v += __shfl_down(v, off, 64);
        st[i] = v;
    }
    if (lane == 0) {
#pragma unroll
        for (int i = 0; i < 9; ++i) red[wave][i] = st[i];
    }
    __syncthreads();
    if (tid < 9)
        partial[(size_t)bid * 9 + tid] =
            (red[0][tid] + red[1][tid]) + (red[2][tid] + red[3][tid]);
}

// ---------------------------------------------------------------------------
// Kernel 2: per-batch. Sum chunk partials (fixed order -> deterministic),
// reconstruct conv3 mean via inclusion-exclusion, MLP, sigmoid, rank.
// ---------------------------------------------------------------------------
__global__ __launch_bounds__(64) void mlp_kernel(
    const float* __restrict__ partial, const float* __restrict__ w3,
    const float* __restrict__ fc1w, const float* __restrict__ fc1b,
    const float* __restrict__ fc2w, const float* __restrict__ fc2b,
    float* __restrict__ idx_out, float* __restrict__ gate_ws,
    int* __restrict__ src_ws)
{
    const int b = blockIdx.x;
    const int t = threadIdx.x;
    __shared__ float mean_s[NC], hid_s[NHID], s_s[NC];

    if (t < NC) {
        const float* base = partial + (size_t)(b * NC + t) * NCHUNK * 9;
        double acc[9];
#pragma unroll
        for (int i = 0; i < 9; ++i) acc[i] = 0.0;
        for (int ch = 0; ch < NCHUNK; ++ch)
#pragma unroll
            for (int i = 0; i < 9; ++i) acc[i] += (double)base[ch * 9 + i];

        float T = (float)acc[0], R0 = (float)acc[1], R251 = (float)acc[2];
        float C0 = (float)acc[3], C251 = (float)acc[4];
        float g00 = (float)acc[5], g0R = (float)acc[6];
        float gR0 = (float)acc[7], gRR = (float)acc[8];

        float ER[3] = {R251, 0.f, R0};
        float EC[3] = {C251, 0.f, C0};
        float CR[3][3] = {{gRR, 0.f, gR0}, {0.f, 0.f, 0.f}, {g0R, 0.f, g00}};
        float m = 0.f;
#pragma unroll
        for (int ky = 0; ky < 3; ++ky)
#pragma unroll
            for (int kx = 0; kx < 3; ++kx) {
                float S = T - ER[ky] - EC[kx] + CR[ky][kx];
                m += w3[t * 9 + ky * 3 + kx] * S;
            }
        mean_s[t] = m * (1.0f / (252.0f * 252.0f));
    }
    __syncthreads();
    if (t < NHID) {
        float a = fc1b[t];
#pragma unroll
        for (int cc = 0; cc < NC; ++cc) a += mean_s[cc] * fc1w[t * NC + cc];
        hid_s[t] = fmaxf(a, 0.f);
    }
    __syncthreads();
    if (t < NC) {
        float a = fc2b[t];
#pragma unroll
        for (int j = 0; j < NHID; ++j) a += hid_s[j] * fc2w[t * NHID + j];
        s_s[t] = 1.0f / (1.0f + expf(-a));
    }
    __syncthreads();
    if (t < NC) {
        float s = s_s[t];
        int rank = 0;
        for (int c2 = 0; c2 < NC; ++c2) {
            float s2 = s_s[c2];
            if (s2 > s || (s2 == s && c2 < t)) rank++;
        }
        float gate = (s * s) / (s * s + 1e-8f);
        idx_out[b * NC + rank] = (float)t;
        gate_ws[b * NC + rank] = gate;
        src_ws[b * NC + rank]  = t;
    }
}

// ---------------------------------------------------------------------------
// Kernel 3: gather + scale. 4 segment-blocks per output slot.
// ---------------------------------------------------------------------------
__global__ __launch_bounds__(256) void gather_kernel(
    const float* __restrict__ x, const float* __restrict__ gate_ws,
    const int* __restrict__ src_ws, float* __restrict__ out)
{
    const int bid = blockIdx.x;
    const int seg = bid & 3;
    const int p   = bid >> 2;            // b*25 + j
    const int b   = p / NC;
    const int j   = p - b * NC;
    const int src = src_ws[p];
    const float gate = gate_ws[p];

    const float4* xp = (const float4*)(x + ((size_t)(b * NC + src)) * (NH * NW))
                       + seg * 4096;
    float* dst;
    if (j < 10) dst = out + ((size_t)(b * 10 + j)) * (NH * NW);
    else dst = out + (size_t)NB * 10 * (NH * NW) + ((size_t)(b * 15 + (j - 10))) * (NH * NW);
    float4* dp = (float4*)dst + seg * 4096;

    const int t = threadIdx.x;
#pragma unroll 4
    for (int i = t; i < 4096; i += 256) {
        float4 v = xp[i];
        v.x *= gate; v.y *= gate; v.z *= gate; v.w *= gate;
        dp[i] = v;
    }
}

extern "C" void kernel_launch(void* const* d_in, const int* in_sizes, int n_in,
                              void* d_out, int out_size, void* d_ws, size_t ws_size,
                              hipStream_t stream)
{
    const float* x    = (const float*)d_in[0];
    const float* w7   = (const float*)d_in[1];
    const float* b7   = (const float*)d_in[2];
    const float* w3   = (const float*)d_in[3];
    const float* fc1w = (const float*)d_in[4];
    const float* fc1b = (const float*)d_in[5];
    const float* fc2w = (const float*)d_in[6];
    const float* fc2b = (const float*)d_in[7];
    float* out = (float*)d_out;

    float* partial = (float*)d_ws;                        // 800*21*9 floats
    float* gate_ws = partial + NB * NC * NCHUNK * 9;      // 800 floats
    int*   src_ws  = (int*)(gate_ws + NB * NC);           // 800 ints

    float* idx_out = out + (size_t)NB * 10 * (NH * NW) + (size_t)NB * 15 * (NH * NW);

    stats_kernel<<<NB * NC * NCHUNK, 256, 0, stream>>>(x, w7, b7, partial);
    mlp_kernel<<<NB, 64, 0, stream>>>(partial, w3, fc1w, fc1b, fc2w, fc2b,
                                      idx_out, gate_ws, src_ws);
    gather_kernel<<<NB * NC * 4, 256, 0, stream>>>(x, gate_ws, src_ws, out);
}